// Round 5
// baseline (402.255 us; speedup 1.0000x reference)
//
#include <hip/hip_runtime.h>

#define C_CH 4
#define F_INN 64
#define F_OUTT 64
#define CF 256  // C_CH * F_IN
#define SCAN_TILE 1024
#define NB_FUSE 16  // nodes per block in fused kernel

// ---------------- init: deg=1 (self loop), cnt=0 ----------------
__global__ void init_kernel(float* __restrict__ deg, int* __restrict__ cnt, int n) {
    int i = blockIdx.x * blockDim.x + threadIdx.x;
    if (i < n) { deg[i] = 1.0f; cnt[i] = 0; }
}

// ---------------- histogram: edge count + weighted degree per target ----------------
__global__ void hist_kernel(const int* __restrict__ col,
                            const float* __restrict__ ew,
                            float* __restrict__ deg, int* __restrict__ cnt, int E) {
    int e = blockIdx.x * blockDim.x + threadIdx.x;
    if (e < E) {
        int d = col[e];
        atomicAdd(&cnt[d], 1);
        unsafeAtomicAdd(&deg[d], ew[e]);
    }
}

// ---------------- exclusive scan of cnt -> offs (3 kernels) ----------------
__global__ __launch_bounds__(SCAN_TILE) void scan1_kernel(const int* __restrict__ cnt,
                                                          int* __restrict__ offs,
                                                          int* __restrict__ blk, int n) {
    __shared__ int s[SCAN_TILE];
    int t = threadIdx.x;
    int g = blockIdx.x * SCAN_TILE + t;
    int v = (g < n) ? cnt[g] : 0;
    s[t] = v;
    __syncthreads();
    for (int d = 1; d < SCAN_TILE; d <<= 1) {
        int x = (t >= d) ? s[t - d] : 0;
        __syncthreads();
        s[t] += x;
        __syncthreads();
    }
    if (g < n) offs[g] = s[t] - v;  // exclusive
    if (t == SCAN_TILE - 1) blk[blockIdx.x] = s[t];
}

__global__ void scan2_kernel(int* __restrict__ blk, int* __restrict__ offs, int nb, int n) {
    if (threadIdx.x == 0 && blockIdx.x == 0) {
        int run = 0;
        for (int i = 0; i < nb; ++i) { int v = blk[i]; blk[i] = run; run += v; }
        offs[n] = run;  // == E
    }
}

__global__ void scan3_kernel(int* __restrict__ offs, const int* __restrict__ blk,
                             int* __restrict__ cnt, int n) {
    int g = blockIdx.x * blockDim.x + threadIdx.x;
    if (g < n) {
        offs[g] += blk[g >> 10];
        cnt[g] = 0;  // reuse as running cursor in scatter
    }
}

// ---------------- scatter edges into CSR buckets: (src, norm) pairs ----------------
__global__ void scatter_kernel(const int* __restrict__ row, const int* __restrict__ col,
                               const float* __restrict__ ew, const float* __restrict__ deg,
                               const int* __restrict__ offs, int* __restrict__ cnt,
                               int2* __restrict__ edata, int E) {
    int e = blockIdx.x * blockDim.x + threadIdx.x;
    if (e < E) {
        int r = row[e];
        int d = col[e];
        float nrm = rsqrtf(deg[r]) * ew[e] * rsqrtf(deg[d]);
        int pos = offs[d] + atomicAdd(&cnt[d], 1);
        edata[pos] = make_int2(r, __float_as_int(nrm));
    }
}

// ---------------- fused aggregate-then-transform: out = (A x) W + b ----------------
// Block = 4 waves, wave c owns channel c. 16 nodes per block.
// Wave holds W[c][:, f=lane] in 64 VGPRs. Per node:
//   agg[k=lane] = (1/deg_v) x[v,c,k] + sum_e norm_e x[src_e,c,k]   (coalesced b32 gathers)
//   out[v,c,f=lane] = sum_k shfl(agg,k) * wr[k] + b[c,f]           (in-wave mat-vec)
__global__ __launch_bounds__(256) void fused_kernel(
        const int* __restrict__ offs, const int2* __restrict__ edata,
        const float* __restrict__ deg, const float* __restrict__ x,
        const float* __restrict__ W, const float* __restrict__ b,
        float* __restrict__ out, int n) {
    int c = threadIdx.x >> 6;
    int lane = threadIdx.x & 63;

    float wr[F_INN];
    const float* __restrict__ Wc = W + c * (F_INN * F_OUTT) + lane;
#pragma unroll
    for (int k = 0; k < F_INN; ++k) wr[k] = Wc[k * F_OUTT];
    float bv = b[c * F_OUTT + lane];

    int n0 = blockIdx.x * NB_FUSE;
    int nend = min(n0 + NB_FUSE, n);
    for (int v = n0; v < nend; ++v) {
        int beg = offs[v];
        int end = offs[v + 1];
        float selfw = 1.0f / deg[v];  // dinv^2; deg >= 1 always
        float a0 = selfw * x[(size_t)v * CF + c * F_INN + lane];
        float a1 = 0.f, a2 = 0.f, a3 = 0.f;

        int j = beg;
        int e4 = beg + ((end - beg) & ~3);
        for (; j < e4; j += 4) {
            int2 e0 = edata[j + 0];
            int2 e1 = edata[j + 1];
            int2 e2 = edata[j + 2];
            int2 e3 = edata[j + 3];
            float x0 = x[(size_t)e0.x * CF + c * F_INN + lane];
            float x1 = x[(size_t)e1.x * CF + c * F_INN + lane];
            float x2 = x[(size_t)e2.x * CF + c * F_INN + lane];
            float x3 = x[(size_t)e3.x * CF + c * F_INN + lane];
            a0 = fmaf(x0, __int_as_float(e0.y), a0);
            a1 = fmaf(x1, __int_as_float(e1.y), a1);
            a2 = fmaf(x2, __int_as_float(e2.y), a2);
            a3 = fmaf(x3, __int_as_float(e3.y), a3);
        }
        for (; j < end; ++j) {
            int2 ed = edata[j];
            float xr = x[(size_t)ed.x * CF + c * F_INN + lane];
            a0 = fmaf(xr, __int_as_float(ed.y), a0);
        }
        float agg = (a0 + a1) + (a2 + a3);

        // in-wave 64x64 mat-vec: broadcast agg[k] via readlane, 4 partial accs
        float s0 = 0.f, s1 = 0.f, s2 = 0.f, s3 = 0.f;
#pragma unroll
        for (int k = 0; k < F_INN; k += 4) {
            s0 = fmaf(__shfl(agg, k + 0), wr[k + 0], s0);
            s1 = fmaf(__shfl(agg, k + 1), wr[k + 1], s1);
            s2 = fmaf(__shfl(agg, k + 2), wr[k + 2], s2);
            s3 = fmaf(__shfl(agg, k + 3), wr[k + 3], s3);
        }
        out[(size_t)v * CF + c * F_OUTT + lane] = ((s0 + s1) + (s2 + s3)) + bv;
    }
}

// ---------------- launch ----------------
extern "C" void kernel_launch(void* const* d_in, const int* in_sizes, int n_in,
                              void* d_out, int out_size, void* d_ws, size_t ws_size,
                              hipStream_t stream) {
    const float* x  = (const float*)d_in[0];
    const int*   ei = (const int*)d_in[1];
    const float* ew = (const float*)d_in[2];
    const float* W  = (const float*)d_in[3];
    const float* b  = (const float*)d_in[4];
    float* out = (float*)d_out;

    int n = in_sizes[0] / (C_CH * F_INN);  // 50000
    int E = in_sizes[2];                    // 800000

    const int* row = ei;       // source
    const int* col = ei + E;   // target

    // workspace layout (256B-aligned chunks)
    auto align_up = [](size_t v) { return (v + 255) & ~(size_t)255; };
    char* p = (char*)d_ws;
    float* deg  = (float*)p;                 p += align_up((size_t)n * 4);
    int*   cnt  = (int*)p;                   p += align_up((size_t)n * 4);
    int*   offs = (int*)p;                   p += align_up(((size_t)n + 1) * 4);
    int*   blk  = (int*)p;                   p += align_up(64 * 4);
    int2*  edata= (int2*)p;

    int nb = (n + SCAN_TILE - 1) / SCAN_TILE;

    init_kernel<<<(n + 255) / 256, 256, 0, stream>>>(deg, cnt, n);
    hist_kernel<<<(E + 255) / 256, 256, 0, stream>>>(col, ew, deg, cnt, E);

    scan1_kernel<<<nb, SCAN_TILE, 0, stream>>>(cnt, offs, blk, n);
    scan2_kernel<<<1, 64, 0, stream>>>(blk, offs, nb, n);
    scan3_kernel<<<(n + 255) / 256, 256, 0, stream>>>(offs, blk, cnt, n);

    scatter_kernel<<<(E + 255) / 256, 256, 0, stream>>>(row, col, ew, deg, offs, cnt, edata, E);

    fused_kernel<<<(n + NB_FUSE - 1) / NB_FUSE, 256, 0, stream>>>(
        offs, edata, deg, x, W, b, out, n);
}

// Round 6
// 294.157 us; speedup vs baseline: 1.3675x; 1.3675x over previous
//
#include <hip/hip_runtime.h>

#define C_CH 4
#define F_INN 64
#define F_OUTT 64
#define CF 256  // C_CH * F_IN
#define SCAN_TILE 1024

// ---------------- init: deg=1 (self loop), cnt=0 ----------------
__global__ void init_kernel(float* __restrict__ deg, int* __restrict__ cnt, int n) {
    int i = blockIdx.x * blockDim.x + threadIdx.x;
    if (i < n) { deg[i] = 1.0f; cnt[i] = 0; }
}

// ---------------- histogram: edge count + weighted degree per target ----------------
__global__ void hist_kernel(const int* __restrict__ col,
                            const float* __restrict__ ew,
                            float* __restrict__ deg, int* __restrict__ cnt, int E) {
    int e = blockIdx.x * blockDim.x + threadIdx.x;
    if (e < E) {
        int d = col[e];
        atomicAdd(&cnt[d], 1);
        unsafeAtomicAdd(&deg[d], ew[e]);
    }
}

// ---------------- exclusive scan of cnt -> offs (3 kernels) ----------------
__global__ __launch_bounds__(SCAN_TILE) void scan1_kernel(const int* __restrict__ cnt,
                                                          int* __restrict__ offs,
                                                          int* __restrict__ blk, int n) {
    __shared__ int s[SCAN_TILE];
    int t = threadIdx.x;
    int g = blockIdx.x * SCAN_TILE + t;
    int v = (g < n) ? cnt[g] : 0;
    s[t] = v;
    __syncthreads();
    for (int d = 1; d < SCAN_TILE; d <<= 1) {
        int x = (t >= d) ? s[t - d] : 0;
        __syncthreads();
        s[t] += x;
        __syncthreads();
    }
    if (g < n) offs[g] = s[t] - v;  // exclusive
    if (t == SCAN_TILE - 1) blk[blockIdx.x] = s[t];
}

__global__ void scan2_kernel(int* __restrict__ blk, int* __restrict__ offs, int nb, int n) {
    if (threadIdx.x == 0 && blockIdx.x == 0) {
        int run = 0;
        for (int i = 0; i < nb; ++i) { int v = blk[i]; blk[i] = run; run += v; }
        offs[n] = run;  // == E
    }
}

__global__ void scan3_kernel(int* __restrict__ offs, const int* __restrict__ blk,
                             int* __restrict__ cnt, int n) {
    int g = blockIdx.x * blockDim.x + threadIdx.x;
    if (g < n) {
        offs[g] += blk[g >> 10];
        cnt[g] = 0;  // reuse as running cursor in scatter
    }
}

// ---------------- scatter edges into CSR buckets: (src, norm) pairs ----------------
__global__ void scatter_kernel(const int* __restrict__ row, const int* __restrict__ col,
                               const float* __restrict__ ew, const float* __restrict__ deg,
                               const int* __restrict__ offs, int* __restrict__ cnt,
                               int2* __restrict__ edata, int E) {
    int e = blockIdx.x * blockDim.x + threadIdx.x;
    if (e < E) {
        int r = row[e];
        int d = col[e];
        float nrm = rsqrtf(deg[r]) * ew[e] * rsqrtf(deg[d]);
        int pos = offs[d] + atomicAdd(&cnt[d], 1);
        edata[pos] = make_int2(r, __float_as_int(nrm));
    }
}

// ---------------- xw: tiled LDS vector-GEMM, per channel ----------------
// Block = (128 nodes) x (64 f) for channel c = blockIdx.y.
// xs[k][node] transposed x-tile (32 KB), ws[k][f] W-tile (16 KB).
// Thread micro-tile: 4 nodes x 8 f. Per k: 3 ds_read_b128 + 32 FMA (VALU-bound).
__global__ __launch_bounds__(256) void xw_gemm_kernel(const float* __restrict__ x,
                                                      const float* __restrict__ W,
                                                      float* __restrict__ xw, int n) {
    __shared__ float xs[64][128];  // [k][node_local]
    __shared__ float ws[64][64];   // [k][f]
    int t = threadIdx.x;
    int c = blockIdx.y;
    int N0 = blockIdx.x * 128;

    // stage W[c] (16 KB, layout-identical copy)
    {
        const float4* Wc4 = reinterpret_cast<const float4*>(W + (size_t)c * F_INN * F_OUTT);
        float4* ws4 = reinterpret_cast<float4*>(&ws[0][0]);
#pragma unroll
        for (int r = 0; r < 4; ++r) ws4[t + 256 * r] = Wc4[t + 256 * r];
    }
    // stage x tile transposed: row r = t>>1, 8 float4 quads per thread
    {
        int r = t >> 1;
        int node = N0 + r;
        const float* __restrict__ xrow = x + (size_t)node * CF + c * F_INN;
#pragma unroll
        for (int rep = 0; rep < 8; ++rep) {
            int q = ((t & 1) << 3) + rep;  // 0..15
            float4 v = (node < n) ? *reinterpret_cast<const float4*>(xrow + 4 * q)
                                  : make_float4(0.f, 0.f, 0.f, 0.f);
            xs[4 * q + 0][r] = v.x;
            xs[4 * q + 1][r] = v.y;
            xs[4 * q + 2][r] = v.z;
            xs[4 * q + 3][r] = v.w;
        }
    }
    __syncthreads();

    int fi = t & 7;   // f octet: f = 8*fi .. 8*fi+7
    int ni = t >> 3;  // node quad: nodes 4*ni .. 4*ni+3
    float acc[4][8];
#pragma unroll
    for (int j = 0; j < 4; ++j)
#pragma unroll
        for (int o = 0; o < 8; ++o) acc[j][o] = 0.f;

#pragma unroll 4
    for (int k = 0; k < F_INN; ++k) {
        float4 a = *reinterpret_cast<const float4*>(&xs[k][4 * ni]);
        float4 b0 = *reinterpret_cast<const float4*>(&ws[k][8 * fi]);
        float4 b1 = *reinterpret_cast<const float4*>(&ws[k][8 * fi + 4]);
        float av[4] = {a.x, a.y, a.z, a.w};
        float bv[8] = {b0.x, b0.y, b0.z, b0.w, b1.x, b1.y, b1.z, b1.w};
#pragma unroll
        for (int j = 0; j < 4; ++j)
#pragma unroll
            for (int o = 0; o < 8; ++o) acc[j][o] = fmaf(av[j], bv[o], acc[j][o]);
    }

#pragma unroll
    for (int j = 0; j < 4; ++j) {
        int node = N0 + 4 * ni + j;
        if (node < n) {
            float* dst = xw + (size_t)node * CF + c * F_OUTT + 8 * fi;
            *reinterpret_cast<float4*>(dst) =
                make_float4(acc[j][0], acc[j][1], acc[j][2], acc[j][3]);
            *reinterpret_cast<float4*>(dst + 4) =
                make_float4(acc[j][4], acc[j][5], acc[j][6], acc[j][7]);
        }
    }
}

// ---------------- gather: one wave per destination node, no atomics ----------------
__global__ __launch_bounds__(256) void gather_kernel(const int* __restrict__ offs,
                                                     const int2* __restrict__ edata,
                                                     const float* __restrict__ deg,
                                                     const float* __restrict__ xw,
                                                     const float* __restrict__ b,
                                                     float* __restrict__ out, int n) {
    int v = (int)((blockIdx.x * 256u + threadIdx.x) >> 6);
    int lane = threadIdx.x & 63;
    if (v >= n) return;

    int beg = offs[v];
    int end = offs[v + 1];
    float s = 1.0f / deg[v];  // dinv^2; deg >= 1 always

    const float4 xv = *reinterpret_cast<const float4*>(xw + (size_t)v * CF + lane * 4);
    const float4 bv = *reinterpret_cast<const float4*>(b + lane * 4);
    float4 acc;
    acc.x = fmaf(xv.x, s, bv.x);
    acc.y = fmaf(xv.y, s, bv.y);
    acc.z = fmaf(xv.z, s, bv.z);
    acc.w = fmaf(xv.w, s, bv.w);

    int j = beg;
    int e4 = beg + ((end - beg) & ~3);
    for (; j < e4; j += 4) {
        int2 e0 = edata[j + 0];
        int2 e1 = edata[j + 1];
        int2 e2 = edata[j + 2];
        int2 e3 = edata[j + 3];
        const float4 x0 = *reinterpret_cast<const float4*>(xw + (size_t)e0.x * CF + lane * 4);
        const float4 x1 = *reinterpret_cast<const float4*>(xw + (size_t)e1.x * CF + lane * 4);
        const float4 x2 = *reinterpret_cast<const float4*>(xw + (size_t)e2.x * CF + lane * 4);
        const float4 x3 = *reinterpret_cast<const float4*>(xw + (size_t)e3.x * CF + lane * 4);
        float n0 = __int_as_float(e0.y), n1 = __int_as_float(e1.y);
        float n2 = __int_as_float(e2.y), n3 = __int_as_float(e3.y);
        acc.x = fmaf(x0.x, n0, acc.x); acc.y = fmaf(x0.y, n0, acc.y);
        acc.z = fmaf(x0.z, n0, acc.z); acc.w = fmaf(x0.w, n0, acc.w);
        acc.x = fmaf(x1.x, n1, acc.x); acc.y = fmaf(x1.y, n1, acc.y);
        acc.z = fmaf(x1.z, n1, acc.z); acc.w = fmaf(x1.w, n1, acc.w);
        acc.x = fmaf(x2.x, n2, acc.x); acc.y = fmaf(x2.y, n2, acc.y);
        acc.z = fmaf(x2.z, n2, acc.z); acc.w = fmaf(x2.w, n2, acc.w);
        acc.x = fmaf(x3.x, n3, acc.x); acc.y = fmaf(x3.y, n3, acc.y);
        acc.z = fmaf(x3.z, n3, acc.z); acc.w = fmaf(x3.w, n3, acc.w);
    }
    for (; j < end; ++j) {
        int2 ed = edata[j];
        float nrm = __int_as_float(ed.y);
        const float4 xr = *reinterpret_cast<const float4*>(xw + (size_t)ed.x * CF + lane * 4);
        acc.x = fmaf(xr.x, nrm, acc.x);
        acc.y = fmaf(xr.y, nrm, acc.y);
        acc.z = fmaf(xr.z, nrm, acc.z);
        acc.w = fmaf(xr.w, nrm, acc.w);
    }
    *reinterpret_cast<float4*>(out + (size_t)v * CF + lane * 4) = acc;
}

// ---------------- launch ----------------
extern "C" void kernel_launch(void* const* d_in, const int* in_sizes, int n_in,
                              void* d_out, int out_size, void* d_ws, size_t ws_size,
                              hipStream_t stream) {
    const float* x  = (const float*)d_in[0];
    const int*   ei = (const int*)d_in[1];
    const float* ew = (const float*)d_in[2];
    const float* W  = (const float*)d_in[3];
    const float* b  = (const float*)d_in[4];
    float* out = (float*)d_out;

    int n = in_sizes[0] / (C_CH * F_INN);  // 50000
    int E = in_sizes[2];                    // 800000

    const int* row = ei;       // source
    const int* col = ei + E;   // target

    // workspace layout (256B-aligned chunks)
    auto align_up = [](size_t v) { return (v + 255) & ~(size_t)255; };
    char* p = (char*)d_ws;
    float* deg  = (float*)p;                 p += align_up((size_t)n * 4);
    int*   cnt  = (int*)p;                   p += align_up((size_t)n * 4);
    int*   offs = (int*)p;                   p += align_up(((size_t)n + 1) * 4);
    int*   blk  = (int*)p;                   p += align_up(64 * 4);
    int2*  edata= (int2*)p;                  p += align_up((size_t)E * 8);
    float* xw   = (float*)p;                 // n*CF floats

    int nb = (n + SCAN_TILE - 1) / SCAN_TILE;

    init_kernel<<<(n + 255) / 256, 256, 0, stream>>>(deg, cnt, n);
    hist_kernel<<<(E + 255) / 256, 256, 0, stream>>>(col, ew, deg, cnt, E);

    scan1_kernel<<<nb, SCAN_TILE, 0, stream>>>(cnt, offs, blk, n);
    scan2_kernel<<<1, 64, 0, stream>>>(blk, offs, nb, n);
    scan3_kernel<<<(n + 255) / 256, 256, 0, stream>>>(offs, blk, cnt, n);

    scatter_kernel<<<(E + 255) / 256, 256, 0, stream>>>(row, col, ew, deg, offs, cnt, edata, E);

    xw_gemm_kernel<<<dim3((n + 127) / 128, C_CH), 256, 0, stream>>>(x, W, xw, n);

    gather_kernel<<<(n * 64 + 255) / 256, 256, 0, stream>>>(offs, edata, deg, xw, b, out, n);
}